// Round 3
// baseline (569.265 us; speedup 1.0000x reference)
//
#include <hip/hip_runtime.h>
#include <cstdint>
#include <math.h>

#define NCLS  20
#define MSZ   512
#define DIM   256
#define HW    16384      // 128*128
#define NPIX  131072     // 4 * 2 * 16384
#define AROWS 10240      // NCLS * MSZ
#define TEMP_INV 10.0f
#define EXP2K 14.4269504088896f   // TEMP_INV * log2(e)

typedef __attribute__((ext_vector_type(8))) short bf16x8;
typedef __attribute__((ext_vector_type(4))) float f32x4;

__device__ __forceinline__ short f2bf(float f) {
    unsigned u = __float_as_uint(f);
    unsigned r = (u + 0x7FFFu + ((u >> 16) & 1u)) >> 16;
    return (short)r;
}
__device__ __forceinline__ float bf2f(short s) {
    return __uint_as_float(((unsigned)(unsigned short)s) << 16);
}

// async global->LDS, 16B/lane, wave-uniform LDS base + lane*16
__device__ __forceinline__ void gld16(const void* g, void* l) {
    __builtin_amdgcn_global_load_lds(
        (const __attribute__((address_space(1))) unsigned int*)(uintptr_t)g,
        (__attribute__((address_space(3))) unsigned int*)(unsigned int)(uintptr_t)l,
        16, 0, 0);
}

// ---------------- K1: per-class ordered selection (labels computed inline) ----------------
__global__ __launch_bounds__(256) void k_select(const int* __restrict__ mg,
                                                const int* __restrict__ ag,
                                                int* __restrict__ sel_idx,
                                                int* __restrict__ counts) {
    int c = blockIdx.x;
    int t = threadIdx.x;
    int lane = t & 63, wv = t >> 6;
    __shared__ int wcnt[4];
    int base = 0;
    for (int chunk = 0; chunk < NPIX; chunk += 256) {
        int n = chunk + t;
        int b = n >> 15, r = n & 32767;
        const int* g = (r < HW) ? mg : ag;
        int p = (r < HW) ? r : (r - HW);
        int h = p >> 7, w = p & 127;
        int lab = g[(((size_t)b * 512) + (size_t)(h << 2)) * 512 + (size_t)(w << 2)];
        if (lab == 255) lab = -1;
        else if (lab == 254) lab = NCLS - 1;
        bool match = (lab == c);
        unsigned long long mask = __ballot(match);
        if (lane == 0) wcnt[wv] = __popcll(mask);
        __syncthreads();
        int prefix = 0;
#pragma unroll
        for (int i = 0; i < 4; ++i) if (i < wv) prefix += wcnt[i];
        int tot = wcnt[0] + wcnt[1] + wcnt[2] + wcnt[3];
        int rank = base + prefix + __popcll(mask & ((1ull << lane) - 1ull));
        if (match && rank < MSZ) sel_idx[c * MSZ + rank] = n;
        base += tot;
        __syncthreads();
        if (base >= MSZ) break;
    }
    if (t == 0) counts[c] = base;
    for (int r2 = base + t; r2 < MSZ; r2 += 256) sel_idx[c * MSZ + r2] = 0;
}

// ---------------- K2: fused gather+normalize (anchors) + bank update (contras) ----------------
// one wave per row; lane handles 4 channels
__global__ __launch_bounds__(256) void k_gatherbank(const float* __restrict__ mainp,
                                                    const float* __restrict__ auxp,
                                                    const int* __restrict__ sel_idx,
                                                    const float* __restrict__ bank,
                                                    const int* __restrict__ counts,
                                                    short* __restrict__ anchorsB,
                                                    short* __restrict__ contrasB,
                                                    int* __restrict__ c_valid) {
    int lane = threadIdx.x & 63, wv = threadIdx.x >> 6;
    int a = blockIdx.x * 4 + wv;
    int n = sel_idx[a];
    int b = n >> 15, r = n & 32767;
    const float* src = (r < HW) ? mainp : auxp;
    int p = (r < HW) ? r : (r - HW);
    const float* gsrc = src + (size_t)b * DIM * HW + p;
    float x[4];
#pragma unroll
    for (int q = 0; q < 4; ++q) x[q] = gsrc[(size_t)(lane * 4 + q) * HW];
    float ss = x[0]*x[0] + x[1]*x[1] + x[2]*x[2] + x[3]*x[3];
#pragma unroll
    for (int o = 1; o < 64; o <<= 1) ss += __shfl_xor(ss, o, 64);
    float scale = 1.0f / fmaxf(sqrtf(ss), 1e-12f);
    float ax[4];
#pragma unroll
    for (int q = 0; q < 4; ++q) ax[q] = x[q] * scale;
    short4 oa;
    oa.x = f2bf(ax[0]); oa.y = f2bf(ax[1]); oa.z = f2bf(ax[2]); oa.w = f2bf(ax[3]);
    *(short4*)&anchorsB[(size_t)a * DIM + lane * 4] = oa;

    int cc = a >> 9, m2 = a & 511;
    bool upd = m2 < counts[cc];
    float4 bv = *(const float4*)&bank[(size_t)a * DIM + lane * 4];
    float u[4];
    u[0] = upd ? 0.999f * bv.x + 0.001f * ax[0] : bv.x;
    u[1] = upd ? 0.999f * bv.y + 0.001f * ax[1] : bv.y;
    u[2] = upd ? 0.999f * bv.z + 0.001f * ax[2] : bv.z;
    u[3] = upd ? 0.999f * bv.w + 0.001f * ax[3] : bv.w;
    float ss2 = u[0]*u[0] + u[1]*u[1] + u[2]*u[2] + u[3]*u[3];
#pragma unroll
    for (int o = 1; o < 64; o <<= 1) ss2 += __shfl_xor(ss2, o, 64);
    float nrm = sqrtf(ss2);
    float inv = 1.0f / fmaxf(nrm, 1e-12f);
    short4 oc;
    oc.x = f2bf(upd ? u[0] * inv : bv.x);
    oc.y = f2bf(upd ? u[1] * inv : bv.y);
    oc.z = f2bf(upd ? u[2] * inv : bv.z);
    oc.w = f2bf(upd ? u[3] * inv : bv.w);
    *(short4*)&contrasB[(size_t)a * DIM + lane * 4] = oc;
    if (lane == 0) c_valid[a] = (nrm > 0.0f) ? 1 : 0;
}

// ---------------- K3: per-class sums of valid contras (S) + valid counts (pcnt) ----------------
__global__ __launch_bounds__(256) void k_csum(const short* __restrict__ contrasB,
                                              const int* __restrict__ c_valid,
                                              float* __restrict__ S,
                                              int* __restrict__ pcnt) {
    int c = blockIdx.x >> 2, mg = blockIdx.x & 3;
    int t = threadIdx.x;
    int row0 = c * MSZ + mg * 128;
    float s = 0.0f;
    int cnt = 0;
    for (int m = 0; m < 128; ++m) {
        int v = c_valid[row0 + m];
        if (v) s += bf2f(contrasB[(size_t)(row0 + m) * DIM + t]);
        cnt += v;
    }
    atomicAdd(&S[c * DIM + t], s);
    if (t == 0) atomicAdd(&pcnt[c], cnt);
}

// ---------------- K4: bf16 MFMA scores + fused sum-exp ----------------
// 128x128 tile; 4 waves 2x2 (64x64 each, 4x4 mfma 16x16x32); BK=64,
// double-buffered LDS, explicit prefetch with raw s_barrier + vmcnt(8),
// XOR-swizzled staging to kill ds_read_b128 bank conflicts.
#define TS 128
#define BK 64
__global__ __launch_bounds__(256) void k_score(const short* __restrict__ A,
                                               const short* __restrict__ Bc,
                                               const int* __restrict__ c_valid,
                                               float* __restrict__ row_sumexp) {
    __shared__ short As[2][TS * BK];
    __shared__ short Bs[2][TS * BK];
    int t = threadIdx.x;
    int lane = t & 63;
    int wv = t >> 6;
    int wr = wv >> 1, wc = wv & 1;
    int row0 = blockIdx.x * TS, col0 = blockIdx.y * TS;

    f32x4 acc[4][4] = {};

    int srow = lane >> 3;                  // row within 8-row slice
    int sslot = lane & 7;                  // 16B LDS slot within row
    int gseg = sslot ^ srow;               // swizzled global 16B segment
    int qr = lane >> 4, qc = lane & 15;

    const short* Ag = A  + (size_t)(row0 + wv * 8 + srow) * DIM + gseg * 8;
    const short* Bg = Bc + (size_t)(col0 + wv * 8 + srow) * DIM + gseg * 8;

    auto stage = [&](int buf, int k0) {
#pragma unroll
        for (int g = 0; g < 4; ++g) {
            gld16(Ag + (size_t)(g * 32) * DIM + k0, &As[buf][(wv * 8 + g * 32) * BK]);
            gld16(Bg + (size_t)(g * 32) * DIM + k0, &Bs[buf][(wv * 8 + g * 32) * BK]);
        }
    };

    stage(0, 0);
#pragma unroll
    for (int k = 0; k < 4; ++k) {
        int cur = k & 1;
        if (k < 3) {
            stage(cur ^ 1, (k + 1) * BK);
            asm volatile("s_waitcnt vmcnt(8)" ::: "memory");   // only current tile's 8 loads
        } else {
            asm volatile("s_waitcnt vmcnt(0)" ::: "memory");
        }
        asm volatile("s_barrier" ::: "memory");
#pragma unroll
        for (int ks = 0; ks < 2; ++ks) {
            bf16x8 af[4], bfv[4];
#pragma unroll
            for (int i = 0; i < 4; ++i) {
                int row = wr * 64 + i * 16 + qc;
                af[i] = *(const bf16x8*)&As[cur][row * BK + (((ks * 4 + qr) ^ (qc & 7)) * 8)];
            }
#pragma unroll
            for (int j = 0; j < 4; ++j) {
                int row = wc * 64 + j * 16 + qc;
                bfv[j] = *(const bf16x8*)&Bs[cur][row * BK + (((ks * 4 + qr) ^ (qc & 7)) * 8)];
            }
#pragma unroll
            for (int i = 0; i < 4; ++i)
#pragma unroll
                for (int j = 0; j < 4; ++j)
                    acc[i][j] = __builtin_amdgcn_mfma_f32_16x16x32_bf16(af[i], bfv[j], acc[i][j], 0, 0, 0);
        }
        if (k < 3) asm volatile("s_barrier" ::: "memory");     // protect cur before restage
    }

    // epilogue: per-row sum of exp over valid cols (pos handled analytically elsewhere)
    float cm[4];
#pragma unroll
    for (int j = 0; j < 4; ++j)
        cm[j] = c_valid[col0 + wc * 64 + j * 16 + qc] ? 1.0f : 0.0f;
#pragma unroll
    for (int i = 0; i < 4; ++i)
#pragma unroll
        for (int r = 0; r < 4; ++r) {
            float e = cm[0] * exp2f(acc[i][0][r] * EXP2K)
                    + cm[1] * exp2f(acc[i][1][r] * EXP2K)
                    + cm[2] * exp2f(acc[i][2][r] * EXP2K)
                    + cm[3] * exp2f(acc[i][3][r] * EXP2K);
#pragma unroll
            for (int o = 1; o < 16; o <<= 1) e += __shfl_xor(e, o, 64);
            if (qc == 0)
                atomicAdd(&row_sumexp[row0 + wr * 64 + i * 16 + qr * 4 + r], e);
        }
}

// ---------------- K5: per-row loss terms (pos_sum = 10 * a . S[class]) ----------------
__global__ __launch_bounds__(256) void k_fin1(const short* __restrict__ anchorsB,
                                              const float* __restrict__ S,
                                              const int* __restrict__ counts,
                                              const int* __restrict__ pcnt,
                                              const float* __restrict__ row_sumexp,
                                              float* __restrict__ lossacc,
                                              int* __restrict__ vcntacc) {
    int lane = threadIdx.x & 63, wv = threadIdx.x >> 6;
    int a = blockIdx.x * 4 + wv;
    int c = a >> 9, m = a & 511;
    short4 a4 = *(const short4*)&anchorsB[(size_t)a * DIM + lane * 4];
    float4 s4 = *(const float4*)&S[c * DIM + lane * 4];
    float dot = bf2f(a4.x) * s4.x + bf2f(a4.y) * s4.y + bf2f(a4.z) * s4.z + bf2f(a4.w) * s4.w;
#pragma unroll
    for (int o = 1; o < 64; o <<= 1) dot += __shfl_xor(dot, o, 64);
    if (lane == 0) {
        int pc = pcnt[c];
        if (m < counts[c] && pc > 0) {
            float lse = logf(row_sumexp[a]);
            float v = (TEMP_INV * dot - (float)pc * lse) / (float)pc;
            atomicAdd(lossacc, v);
            atomicAdd(vcntacc, 1);
        }
    }
}

__global__ void k_fin2(const float* __restrict__ lossacc,
                       const int* __restrict__ vcntacc,
                       float* __restrict__ out) {
    int v = vcntacc[0];
    out[0] = -lossacc[0] / (float)(v > 0 ? v : 1);
}

// ---------------- launch ----------------
extern "C" void kernel_launch(void* const* d_in, const int* in_sizes, int n_in,
                              void* d_out, int out_size, void* d_ws, size_t ws_size,
                              hipStream_t stream) {
    const float* main_proj = (const float*)d_in[0];
    const int*   main_gt   = (const int*)d_in[1];
    const float* aux_proj  = (const float*)d_in[2];
    const int*   aux_gt    = (const int*)d_in[3];
    const float* bank      = (const float*)d_in[4];
    float* out = (float*)d_out;

    char* ws = (char*)d_ws;
    int*   sel_idx    = (int*)ws;                    // 40960 B
    int*   counts     = (int*)(ws + 40960);          // 256 B
    int*   c_valid    = (int*)(ws + 41216);          // 40960 B
    float* row_sumexp = (float*)(ws + 82176);        // 40960 B  [zero region start]
    float* S          = (float*)(ws + 123136);       // 20480 B
    int*   pcnt       = (int*)(ws + 143616);         // 128 B
    float* lossacc    = (float*)(ws + 143744);       // 4 B
    int*   vcntacc    = (int*)(ws + 143748);         // 4 B (+pad)
    short* anchorsB   = (short*)(ws + 143872);       // 5242880 B
    short* contrasB   = (short*)(ws + 5386752);      // 5242880 B

    hipMemsetAsync(ws + 82176, 0, 143872 - 82176, stream);
    k_select<<<NCLS, 256, 0, stream>>>(main_gt, aux_gt, sel_idx, counts);
    k_gatherbank<<<AROWS / 4, 256, 0, stream>>>(main_proj, aux_proj, sel_idx, bank,
                                                counts, anchorsB, contrasB, c_valid);
    k_csum<<<NCLS * 4, 256, 0, stream>>>(contrasB, c_valid, S, pcnt);
    dim3 grid(AROWS / TS, AROWS / TS);
    k_score<<<grid, 256, 0, stream>>>(anchorsB, contrasB, c_valid, row_sumexp);
    k_fin1<<<AROWS / 4, 256, 0, stream>>>(anchorsB, S, counts, pcnt, row_sumexp,
                                          lossacc, vcntacc);
    k_fin2<<<1, 1, 0, stream>>>(lossacc, vcntacc, out);
}

// Round 4
// 336.492 us; speedup vs baseline: 1.6918x; 1.6918x over previous
//
#include <hip/hip_runtime.h>
#include <cstdint>
#include <math.h>

#define NCLS  20
#define MSZ   512
#define DIM   256
#define HW    16384      // 128*128
#define NPIX  131072     // 4 * 2 * 16384
#define AROWS 10240      // NCLS * MSZ
#define TEMP_INV 10.0f
#define EXP2K 14.4269504088896f   // TEMP_INV * log2(e)

typedef __attribute__((ext_vector_type(8))) short bf16x8;
typedef __attribute__((ext_vector_type(4))) float f32x4;

__device__ __forceinline__ short f2bf(float f) {
    unsigned u = __float_as_uint(f);
    unsigned r = (u + 0x7FFFu + ((u >> 16) & 1u)) >> 16;
    return (short)r;
}
__device__ __forceinline__ float bf2f(short s) {
    return __uint_as_float(((unsigned)(unsigned short)s) << 16);
}

// async global->LDS, 16B/lane, wave-uniform LDS base + lane*16
__device__ __forceinline__ void gld16(const void* g, void* l) {
    __builtin_amdgcn_global_load_lds(
        (const __attribute__((address_space(1))) unsigned int*)(uintptr_t)g,
        (__attribute__((address_space(3))) unsigned int*)(unsigned int)(uintptr_t)l,
        16, 0, 0);
}

// ---------------- K1: per-class ordered selection (labels inline) ----------------
__global__ __launch_bounds__(256) void k_select(const int* __restrict__ mg,
                                                const int* __restrict__ ag,
                                                int* __restrict__ sel_idx,
                                                int* __restrict__ counts) {
    int c = blockIdx.x;
    int t = threadIdx.x;
    int lane = t & 63, wv = t >> 6;
    __shared__ int wcnt[4];
    int base = 0;
    for (int chunk = 0; chunk < NPIX; chunk += 256) {
        int n = chunk + t;
        int b = n >> 15, r = n & 32767;
        const int* g = (r < HW) ? mg : ag;
        int p = (r < HW) ? r : (r - HW);
        int h = p >> 7, w = p & 127;
        int lab = g[(((size_t)b * 512) + (size_t)(h << 2)) * 512 + (size_t)(w << 2)];
        if (lab == 255) lab = -1;
        else if (lab == 254) lab = NCLS - 1;
        bool match = (lab == c);
        unsigned long long mask = __ballot(match);
        if (lane == 0) wcnt[wv] = __popcll(mask);
        __syncthreads();
        int prefix = 0;
#pragma unroll
        for (int i = 0; i < 4; ++i) if (i < wv) prefix += wcnt[i];
        int tot = wcnt[0] + wcnt[1] + wcnt[2] + wcnt[3];
        int rank = base + prefix + __popcll(mask & ((1ull << lane) - 1ull));
        if (match && rank < MSZ) sel_idx[c * MSZ + rank] = n;
        base += tot;
        __syncthreads();
        if (base >= MSZ) break;
    }
    if (t == 0) counts[c] = base;
    for (int r2 = base + t; r2 < MSZ; r2 += 256) sel_idx[c * MSZ + r2] = 0;
}

// ---------------- K2: fused gather+normalize + bank update ----------------
__global__ __launch_bounds__(256) void k_gatherbank(const float* __restrict__ mainp,
                                                    const float* __restrict__ auxp,
                                                    const int* __restrict__ sel_idx,
                                                    const float* __restrict__ bank,
                                                    const int* __restrict__ counts,
                                                    short* __restrict__ anchorsB,
                                                    short* __restrict__ contrasB,
                                                    int* __restrict__ c_valid) {
    int lane = threadIdx.x & 63, wv = threadIdx.x >> 6;
    int a = blockIdx.x * 4 + wv;
    int n = sel_idx[a];
    int b = n >> 15, r = n & 32767;
    const float* src = (r < HW) ? mainp : auxp;
    int p = (r < HW) ? r : (r - HW);
    const float* gsrc = src + (size_t)b * DIM * HW + p;
    float x[4];
#pragma unroll
    for (int q = 0; q < 4; ++q) x[q] = gsrc[(size_t)(lane * 4 + q) * HW];
    float ss = x[0]*x[0] + x[1]*x[1] + x[2]*x[2] + x[3]*x[3];
#pragma unroll
    for (int o = 1; o < 64; o <<= 1) ss += __shfl_xor(ss, o, 64);
    float scale = 1.0f / fmaxf(sqrtf(ss), 1e-12f);
    float ax[4];
#pragma unroll
    for (int q = 0; q < 4; ++q) ax[q] = x[q] * scale;
    short4 oa;
    oa.x = f2bf(ax[0]); oa.y = f2bf(ax[1]); oa.z = f2bf(ax[2]); oa.w = f2bf(ax[3]);
    *(short4*)&anchorsB[(size_t)a * DIM + lane * 4] = oa;

    int cc = a >> 9, m2 = a & 511;
    bool upd = m2 < counts[cc];
    float4 bv = *(const float4*)&bank[(size_t)a * DIM + lane * 4];
    float u[4];
    u[0] = upd ? 0.999f * bv.x + 0.001f * ax[0] : bv.x;
    u[1] = upd ? 0.999f * bv.y + 0.001f * ax[1] : bv.y;
    u[2] = upd ? 0.999f * bv.z + 0.001f * ax[2] : bv.z;
    u[3] = upd ? 0.999f * bv.w + 0.001f * ax[3] : bv.w;
    float ss2 = u[0]*u[0] + u[1]*u[1] + u[2]*u[2] + u[3]*u[3];
#pragma unroll
    for (int o = 1; o < 64; o <<= 1) ss2 += __shfl_xor(ss2, o, 64);
    float nrm = sqrtf(ss2);
    float inv = 1.0f / fmaxf(nrm, 1e-12f);
    short4 oc;
    oc.x = f2bf(upd ? u[0] * inv : bv.x);
    oc.y = f2bf(upd ? u[1] * inv : bv.y);
    oc.z = f2bf(upd ? u[2] * inv : bv.z);
    oc.w = f2bf(upd ? u[3] * inv : bv.w);
    *(short4*)&contrasB[(size_t)a * DIM + lane * 4] = oc;
    if (lane == 0) c_valid[a] = (nrm > 0.0f) ? 1 : 0;
}

// ---------------- K3: per-class sums of valid contras + valid counts ----------------
__global__ __launch_bounds__(256) void k_csum(const short* __restrict__ contrasB,
                                              const int* __restrict__ c_valid,
                                              float* __restrict__ S,
                                              int* __restrict__ pcnt) {
    int c = blockIdx.x >> 2, mg = blockIdx.x & 3;
    int t = threadIdx.x;
    int row0 = c * MSZ + mg * 128;
    float s = 0.0f;
    int cnt = 0;
    for (int m = 0; m < 128; ++m) {
        int v = c_valid[row0 + m];
        if (v) s += bf2f(contrasB[(size_t)(row0 + m) * DIM + t]);
        cnt += v;
    }
    atomicAdd(&S[c * DIM + t], s);
    if (t == 0) atomicAdd(&pcnt[c], cnt);
}

// ---------------- K4: bf16 MFMA scores + fused sum-exp (R2-proven structure) ----------------
// 128x128 tile; 4 waves 2x2; each wave 64x64 via 4x4 mfma 16x16x32; BK=32 single-buffered.
#define TS 128
#define BK 32
__global__ __launch_bounds__(256) void k_score(const short* __restrict__ A,
                                               const short* __restrict__ Bc,
                                               const int* __restrict__ c_valid,
                                               float* __restrict__ row_sumexp) {
    __shared__ short As[TS * BK];
    __shared__ short Bs[TS * BK];
    int t = threadIdx.x;
    int lane = t & 63;
    int wv = t >> 6;
    int wr = wv >> 1, wc = wv & 1;
    int row0 = blockIdx.x * TS, col0 = blockIdx.y * TS;

    f32x4 acc[4][4] = {};

    int lrow = lane >> 2;         // 0..15
    int lseg = lane & 3;          // 0..3
    int qr = lane >> 4;           // 0..3
    int qc = lane & 15;           // 0..15

    const short* Abase = A  + (size_t)(row0 + wv * 32) * DIM;
    const short* Bbase = Bc + (size_t)(col0 + wv * 32) * DIM;
    short* AsW = &As[(wv * 32) * BK];
    short* BsW = &Bs[(wv * 32) * BK];

    for (int k0 = 0; k0 < DIM; k0 += BK) {
        __syncthreads();
#pragma unroll
        for (int g = 0; g < 2; ++g) {
            gld16(Abase + (size_t)(g * 16 + lrow) * DIM + k0 + lseg * 8, AsW + (g * 16) * BK);
            gld16(Bbase + (size_t)(g * 16 + lrow) * DIM + k0 + lseg * 8, BsW + (g * 16) * BK);
        }
        asm volatile("s_waitcnt vmcnt(0)" ::: "memory");
        __syncthreads();

        bf16x8 af[4], bfv[4];
#pragma unroll
        for (int i = 0; i < 4; ++i)
            af[i] = *(const bf16x8*)&As[(wr * 64 + i * 16 + qc) * BK + qr * 8];
#pragma unroll
        for (int j = 0; j < 4; ++j)
            bfv[j] = *(const bf16x8*)&Bs[(wc * 64 + j * 16 + qc) * BK + qr * 8];
#pragma unroll
        for (int i = 0; i < 4; ++i)
#pragma unroll
            for (int j = 0; j < 4; ++j)
                acc[i][j] = __builtin_amdgcn_mfma_f32_16x16x32_bf16(af[i], bfv[j], acc[i][j], 0, 0, 0);
    }

    // epilogue: per-row sum of exp over valid cols (positives handled analytically)
    float cm[4];
#pragma unroll
    for (int j = 0; j < 4; ++j)
        cm[j] = c_valid[col0 + wc * 64 + j * 16 + qc] ? 1.0f : 0.0f;
#pragma unroll
    for (int i = 0; i < 4; ++i)
#pragma unroll
        for (int r = 0; r < 4; ++r) {
            float e = cm[0] * exp2f(acc[i][0][r] * EXP2K)
                    + cm[1] * exp2f(acc[i][1][r] * EXP2K)
                    + cm[2] * exp2f(acc[i][2][r] * EXP2K)
                    + cm[3] * exp2f(acc[i][3][r] * EXP2K);
#pragma unroll
            for (int o = 1; o < 16; o <<= 1) e += __shfl_xor(e, o, 64);
            if (qc == 0)
                atomicAdd(&row_sumexp[row0 + wr * 64 + i * 16 + qr * 4 + r], e);
        }
}

// ---------------- K5: per-row loss terms (no global atomics) ----------------
__global__ __launch_bounds__(256) void k_fin1(const short* __restrict__ anchorsB,
                                              const float* __restrict__ S,
                                              const int* __restrict__ counts,
                                              const int* __restrict__ pcnt,
                                              const float* __restrict__ row_sumexp,
                                              float* __restrict__ rowterm,
                                              int* __restrict__ rowvld) {
    int lane = threadIdx.x & 63, wv = threadIdx.x >> 6;
    int a = blockIdx.x * 4 + wv;
    int c = a >> 9, m = a & 511;
    short4 a4 = *(const short4*)&anchorsB[(size_t)a * DIM + lane * 4];
    float4 s4 = *(const float4*)&S[c * DIM + lane * 4];
    float dot = bf2f(a4.x) * s4.x + bf2f(a4.y) * s4.y + bf2f(a4.z) * s4.z + bf2f(a4.w) * s4.w;
#pragma unroll
    for (int o = 1; o < 64; o <<= 1) dot += __shfl_xor(dot, o, 64);
    if (lane == 0) {
        int pc = pcnt[c];
        bool va = (m < counts[c]) && (pc > 0);
        float v = 0.0f;
        if (va) {
            float lse = logf(row_sumexp[a]);
            v = (TEMP_INV * dot - (float)pc * lse) / (float)pc;
        }
        rowterm[a] = v;
        rowvld[a] = va ? 1 : 0;
    }
}

// ---------------- K6: final reduction ----------------
__global__ __launch_bounds__(256) void k_fin2(const float* __restrict__ rowterm,
                                              const int* __restrict__ rowvld,
                                              float* __restrict__ out) {
    __shared__ float sred[4];
    __shared__ int cred[4];
    int t = threadIdx.x;
    float lsum = 0.0f;
    int vcnt = 0;
    for (int a = t; a < AROWS; a += 256) {
        lsum += rowterm[a];
        vcnt += rowvld[a];
    }
#pragma unroll
    for (int o = 32; o > 0; o >>= 1) {
        lsum += __shfl_down(lsum, o, 64);
        vcnt += __shfl_down(vcnt, o, 64);
    }
    if ((t & 63) == 0) { sred[t >> 6] = lsum; cred[t >> 6] = vcnt; }
    __syncthreads();
    if (t == 0) {
        float L = sred[0] + sred[1] + sred[2] + sred[3];
        int V = cred[0] + cred[1] + cred[2] + cred[3];
        out[0] = -L / (float)(V > 0 ? V : 1);
    }
}

// ---------------- launch ----------------
extern "C" void kernel_launch(void* const* d_in, const int* in_sizes, int n_in,
                              void* d_out, int out_size, void* d_ws, size_t ws_size,
                              hipStream_t stream) {
    const float* main_proj = (const float*)d_in[0];
    const int*   main_gt   = (const int*)d_in[1];
    const float* aux_proj  = (const float*)d_in[2];
    const int*   aux_gt    = (const int*)d_in[3];
    const float* bank      = (const float*)d_in[4];
    float* out = (float*)d_out;

    char* ws = (char*)d_ws;
    int*   sel_idx    = (int*)ws;                    // 40960 B
    int*   counts     = (int*)(ws + 40960);          // 256 B
    int*   c_valid    = (int*)(ws + 41216);          // 40960 B
    float* row_sumexp = (float*)(ws + 82176);        // 40960 B  [zero region start]
    float* S          = (float*)(ws + 123136);       // 20480 B
    int*   pcnt       = (int*)(ws + 143616);         // 256 B    [zero region end]
    float* rowterm    = (float*)(ws + 143872);       // 40960 B
    int*   rowvld     = (int*)(ws + 184832);         // 40960 B
    short* anchorsB   = (short*)(ws + 225792);       // 5242880 B
    short* contrasB   = (short*)(ws + 5468672);      // 5242880 B

    hipMemsetAsync(ws + 82176, 0, 143872 - 82176, stream);
    k_select<<<NCLS, 256, 0, stream>>>(main_gt, aux_gt, sel_idx, counts);
    k_gatherbank<<<AROWS / 4, 256, 0, stream>>>(main_proj, aux_proj, sel_idx, bank,
                                                counts, anchorsB, contrasB, c_valid);
    k_csum<<<NCLS * 4, 256, 0, stream>>>(contrasB, c_valid, S, pcnt);
    dim3 grid(AROWS / TS, AROWS / TS);
    k_score<<<grid, 256, 0, stream>>>(anchorsB, contrasB, c_valid, row_sumexp);
    k_fin1<<<AROWS / 4, 256, 0, stream>>>(anchorsB, S, counts, pcnt, row_sumexp,
                                          rowterm, rowvld);
    k_fin2<<<1, 256, 0, stream>>>(rowterm, rowvld, out);
}